// Round 9
// baseline (310.378 us; speedup 1.0000x reference)
//
#include <hip/hip_runtime.h>
#include <stdint.h>

// Round 9: attn restructure — QBLK=128 (32 q-rows/wave, amortizes K/V staging
// and LDS reads 2x over MFMA), T13 defer-max rescale skip, T5 setprio around
// MFMA clusters. GEMMs/LN/transposes frozen from round 8 for attribution.

typedef unsigned short u16;
typedef unsigned int u32;
typedef __attribute__((ext_vector_type(4))) float f32x4;
typedef __attribute__((ext_vector_type(8))) short s16x8;

__device__ __forceinline__ u16 f2bf(float f) {
  u32 u = __builtin_bit_cast(u32, f);
  u += 0x7fffu + ((u >> 16) & 1u);
  return (u16)(u >> 16);
}
// 8-byte-aligned s16x8 load (2 x b64) for odd-stride LDS rows
__device__ __forceinline__ s16x8 ld_s16x8_a8(const u16* p) {
  union { uint2 d[2]; s16x8 v; } u;
  u.d[0] = *(const uint2*)p;
  u.d[1] = *(const uint2*)(p + 4);
  return u.v;
}
// async global->LDS, 16B per lane; lds dest must be wave-uniform base (lane*16 implicit)
__device__ __forceinline__ void gload16(const u16* g, u16* lds_base) {
  __builtin_amdgcn_global_load_lds(
      (const __attribute__((address_space(1))) void*)g,
      (__attribute__((address_space(3))) void*)lds_base, 16, 0, 0);
}

// ---------------------------------------------------------------------------
// Tiled transpose fp32 -> bf16: dst[(c)*dstStride + r] = src[r*Ccols + c]
// ---------------------------------------------------------------------------
__global__ __launch_bounds__(256) void transpose_f32_bf16(
    const float* __restrict__ src, u16* __restrict__ dst,
    int Ccols, long srcZ, long dstZ, int dstStride) {
  __shared__ float t[64][65];
  const float* s = src + (size_t)blockIdx.z * srcZ;
  u16* d = dst + (size_t)blockIdx.z * dstZ;
  const int r0 = blockIdx.y * 64, c0 = blockIdx.x * 64;
  const int tr = threadIdx.x >> 4, tc4 = (threadIdx.x & 15) * 4;
#pragma unroll
  for (int p = 0; p < 4; ++p) {
    int r = p * 16 + tr;
    float4 v = *(const float4*)(s + (size_t)(r0 + r) * Ccols + c0 + tc4);
    t[r][tc4 + 0] = v.x; t[r][tc4 + 1] = v.y;
    t[r][tc4 + 2] = v.z; t[r][tc4 + 3] = v.w;
  }
  __syncthreads();
#pragma unroll
  for (int p = 0; p < 4; ++p) {
    int c = p * 16 + tr;
    uint2 pk;
    pk.x = (u32)f2bf(t[tc4 + 0][c]) | ((u32)f2bf(t[tc4 + 1][c]) << 16);
    pk.y = (u32)f2bf(t[tc4 + 2][c]) | ((u32)f2bf(t[tc4 + 3][c]) << 16);
    *(uint2*)(d + (size_t)(c0 + c) * dstStride + r0 + tc4) = pk;
  }
}

// ---------------------------------------------------------------------------
// LayerNorm: one block per row of 1024 fp32; out bf16.
// ---------------------------------------------------------------------------
__global__ __launch_bounds__(256) void ln_kernel(
    const float* __restrict__ x, const float* __restrict__ g,
    const float* __restrict__ be, u16* __restrict__ out) {
  const int row = blockIdx.x, tid = threadIdx.x;
  const float* xr = x + (size_t)row * 1024;
  float4 v = *(const float4*)(xr + tid * 4);
  float s = v.x + v.y + v.z + v.w;
  float q = v.x * v.x + v.y * v.y + v.z * v.z + v.w * v.w;
#pragma unroll
  for (int off = 32; off > 0; off >>= 1) {
    s += __shfl_down(s, off);
    q += __shfl_down(q, off);
  }
  __shared__ float red[8];
  const int wid = tid >> 6, lane = tid & 63;
  if (lane == 0) { red[wid] = s; red[wid + 4] = q; }
  __syncthreads();
  s = red[0] + red[1] + red[2] + red[3];
  q = red[4] + red[5] + red[6] + red[7];
  const float mu = s * (1.f / 1024.f);
  const float var = q * (1.f / 1024.f) - mu * mu;
  const float rs = rsqrtf(var + 1e-5f);
  float4 gv = *(const float4*)(g + tid * 4);
  float4 bv = *(const float4*)(be + tid * 4);
  float o0 = (v.x - mu) * rs * gv.x + bv.x;
  float o1 = (v.y - mu) * rs * gv.y + bv.y;
  float o2 = (v.z - mu) * rs * gv.z + bv.z;
  float o3 = (v.w - mu) * rs * gv.w + bv.w;
  uint2 pk;
  pk.x = (u32)f2bf(o0) | ((u32)f2bf(o1) << 16);
  pk.y = (u32)f2bf(o2) | ((u32)f2bf(o3) << 16);
  *(uint2*)(out + (size_t)row * 1024 + tid * 4) = pk;
}

// ---------------------------------------------------------------------------
// GEMM: C[M,N] = A[M,K] @ BT[N,K]^T  (+ bias, relu, residual per EPI)
// EPI 0: -> bf16.  EPI 1: +bias, relu -> bf16.  EPI 2: +bias +resid -> fp32.
// BMx128 tile, BK=64, 256 threads (4 waves 2x2). m97 structure.
// ---------------------------------------------------------------------------
template <int EPI, int BM>
__global__ __launch_bounds__(256) void gemm_kernel(
    const u16* __restrict__ A, const u16* __restrict__ BT,
    const float* __restrict__ bias, const float* __restrict__ resid,
    void* __restrict__ out, int M, int N, int K) {
  __shared__ u16 sA[BM][64];
  __shared__ u16 sB[128][64];
  const int tid = threadIdx.x;
  const int m0 = blockIdx.y * BM, n0 = blockIdx.x * 128;
  const int wid = tid >> 6, lane = tid & 63;
  const int wr = (wid >> 1) * (BM / 2), wc = (wid & 1) * 64;
  const int l15 = lane & 15, g = lane >> 4;
  constexpr int MR = BM / 32;
  f32x4 acc[MR][4] = {};
  const int lr = lane >> 3;
  const int cswz = ((lane & 7) * 8) ^ (lr << 3);  // u16 units

  for (int k0 = 0; k0 < K; k0 += 64) {
    __syncthreads();
#pragma unroll
    for (int p = 0; p < MR; ++p) {
      const int row = (p * 4 + wid) * 8 + lr;  // row & 7 == lr
      gload16(A + (size_t)(m0 + row) * K + k0 + cswz, &sA[(p * 4 + wid) * 8][0]);
    }
#pragma unroll
    for (int p = 0; p < 4; ++p) {
      const int row = (p * 4 + wid) * 8 + lr;
      gload16(BT + (size_t)(n0 + row) * K + k0 + cswz, &sB[(p * 4 + wid) * 8][0]);
    }
    __syncthreads();  // drains vmcnt(0) before any ds_read
#pragma unroll
    for (int kk = 0; kk < 64; kk += 32) {
      s16x8 af[MR], bf[4];
#pragma unroll
      for (int m = 0; m < MR; ++m) {
        const int R = wr + m * 16 + l15;
        af[m] = *(const s16x8*)(&sA[R][(kk + g * 8) ^ ((R & 7) << 3)]);
      }
#pragma unroll
      for (int n = 0; n < 4; ++n) {
        const int R = wc + n * 16 + l15;
        bf[n] = *(const s16x8*)(&sB[R][(kk + g * 8) ^ ((R & 7) << 3)]);
      }
#pragma unroll
      for (int m = 0; m < MR; ++m)
#pragma unroll
        for (int n = 0; n < 4; ++n)
          acc[m][n] = __builtin_amdgcn_mfma_f32_16x16x32_bf16(af[m], bf[n], acc[m][n], 0, 0, 0);
    }
  }

#pragma unroll
  for (int m = 0; m < MR; ++m) {
#pragma unroll
    for (int n = 0; n < 4; ++n) {
      const int col = n0 + wc + n * 16 + l15;
      float bv = 0.f;
      if (EPI >= 1) bv = bias[col];
#pragma unroll
      for (int i = 0; i < 4; ++i) {
        const int row = m0 + wr + m * 16 + g * 4 + i;
        float v = acc[m][n][i];
        if (EPI >= 1) v += bv;
        if (EPI == 1) v = fmaxf(v, 0.f);
        if (EPI == 2) {
          v += resid[(size_t)row * N + col];
          ((float*)out)[(size_t)row * N + col] = v;
        } else {
          ((u16*)out)[(size_t)row * N + col] = f2bf(v);
        }
      }
    }
  }
}

// ---------------------------------------------------------------------------
// MFMA causal flash attention. QBLK=128: block handles q in [qb*128, qb*128+128),
// wave w owns 32 q-rows (2 m-tiles of 16). KV tiles of 64; T14 reg-prefetch;
// T13 defer-max; T5 setprio. grid (16, B*H) heavy-first (qb = 15 - bx).
// ---------------------------------------------------------------------------
__global__ __launch_bounds__(256) void attn_mfma_kernel(
    const u16* __restrict__ qkv, u16* __restrict__ o) {
  __shared__ u16 sK[64][72];     // [s][d]
  __shared__ u16 sVt[64][68];    // [d][s]
  __shared__ u16 sP[4][32][72];  // per-wave P strip [q][s]
  const int tid = threadIdx.x;
  const int b = blockIdx.y >> 4, h = blockIdx.y & 15;
  const int w = tid >> 6, lane = tid & 63;
  const int l15 = lane & 15, g = lane >> 4;
  const float c = 0.125f * 1.4426950408889634f;  // scale * log2(e)
  const int ks_r = tid >> 2, ks_c = (tid & 3) * 16;
  const int vs_s = tid & 63, vs_d = (tid >> 6) * 8;
  const u16* kbase = qkv + (size_t)(b * 2048) * 3072 + 1024 + h * 64;
  const u16* vbase = kbase + 1024;
  const int qb = 15 - (int)blockIdx.x;  // heavy blocks dispatched first
  const int qw = qb * 128 + w * 32;     // wave q base

  // Q fragments: 2 m-tiles x 2 k-halves (A-frag: row=l15, k=32*half+g*8+j)
  s16x8 qf[2][2];
#pragma unroll
  for (int mt = 0; mt < 2; ++mt) {
    const size_t qrow = (size_t)(b * 2048 + qw + mt * 16 + l15);
    qf[mt][0] = *(const s16x8*)(qkv + qrow * 3072 + h * 64 + g * 8);
    qf[mt][1] = *(const s16x8*)(qkv + qrow * 3072 + h * 64 + 32 + g * 8);
  }

  f32x4 oacc[2][4] = {};  // O[mt][dt]: row q=qw+mt*16+4g+i, col d=dt*16+l15
  float mrow[2][4], lrow[2][4];
#pragma unroll
  for (int mt = 0; mt < 2; ++mt)
#pragma unroll
    for (int i = 0; i < 4; ++i) { mrow[mt][i] = -1e30f; lrow[mt][i] = 0.f; }

  const int nt = 2 * qb + 2;
  // T14: prefetch tile 0 into regs
  uint4 kr0, kr1, vr0, vr1;
  {
    const u16* kp = kbase + (size_t)(ks_r)*3072 + ks_c;
    kr0 = *(const uint4*)kp; kr1 = *(const uint4*)(kp + 8);
    const u16* vp = vbase + (size_t)(vs_s)*3072 + vs_d;
    vr0 = *(const uint4*)vp; vr1 = *(const uint4*)(vp + 32);
  }
  for (int t = 0; t < nt; ++t) {
    __syncthreads();  // all waves done with previous tile's LDS
    *(uint4*)(&sK[ks_r][ks_c]) = kr0;
    *(uint4*)(&sK[ks_r][ks_c + 8]) = kr1;
    {
      union { uint4 q4; u16 e[8]; } va, vb;
      va.q4 = vr0; vb.q4 = vr1;
#pragma unroll
      for (int j = 0; j < 8; ++j) sVt[vs_d + j][vs_s] = va.e[j];
#pragma unroll
      for (int j = 0; j < 8; ++j) sVt[vs_d + 32 + j][vs_s] = vb.e[j];
    }
    __syncthreads();
    // issue next tile's global loads; latency hides under compute below
    if (t + 1 < nt) {
      const u16* kp = kbase + (size_t)((t + 1) * 64 + ks_r) * 3072 + ks_c;
      kr0 = *(const uint4*)kp; kr1 = *(const uint4*)(kp + 8);
      const u16* vp = vbase + (size_t)((t + 1) * 64 + vs_s) * 3072 + vs_d;
      vr0 = *(const uint4*)vp; vr1 = *(const uint4*)(vp + 32);
    }

    // QK^T: S[32 q][64 s]; K-frag reads shared across both m-tiles
    f32x4 st[2][4];
    __builtin_amdgcn_s_setprio(1);
#pragma unroll
    for (int n = 0; n < 4; ++n) {
      s16x8 k0 = *(const s16x8*)(&sK[n * 16 + l15][g * 8]);
      s16x8 k1 = *(const s16x8*)(&sK[n * 16 + l15][32 + g * 8]);
#pragma unroll
      for (int mt = 0; mt < 2; ++mt) {
        f32x4 a = {};
        a = __builtin_amdgcn_mfma_f32_16x16x32_bf16(qf[mt][0], k0, a, 0, 0, 0);
        a = __builtin_amdgcn_mfma_f32_16x16x32_bf16(qf[mt][1], k1, a, 0, 0, 0);
        st[mt][n] = a;
      }
    }
    __builtin_amdgcn_s_setprio(0);
    if (t >= 2 * qb) {  // causal mask (diagonal spans the last two tiles)
#pragma unroll
      for (int mt = 0; mt < 2; ++mt)
#pragma unroll
        for (int n = 0; n < 4; ++n)
#pragma unroll
          for (int i = 0; i < 4; ++i) {
            const int s_abs = t * 64 + n * 16 + l15;
            const int q_abs = qw + mt * 16 + 4 * g + i;
            if (s_abs > q_abs) st[mt][n][i] = -1e30f;
          }
    }
    // per-row max (reduce across the 16-lane group)
    float pm[2][4];
#pragma unroll
    for (int mt = 0; mt < 2; ++mt)
#pragma unroll
      for (int i = 0; i < 4; ++i)
        pm[mt][i] = fmaxf(fmaxf(st[mt][0][i], st[mt][1][i]),
                          fmaxf(st[mt][2][i], st[mt][3][i]));
#pragma unroll
    for (int msk = 1; msk < 16; msk <<= 1)
#pragma unroll
      for (int mt = 0; mt < 2; ++mt)
#pragma unroll
        for (int i = 0; i < 4; ++i) pm[mt][i] = fmaxf(pm[mt][i], __shfl_xor(pm[mt][i], msk));
    // T13 defer-max: only rescale when the tile max meaningfully exceeds mrow
    bool need = false;
#pragma unroll
    for (int mt = 0; mt < 2; ++mt)
#pragma unroll
      for (int i = 0; i < 4; ++i) need = need || (pm[mt][i] > mrow[mt][i] + 16.f);
    if (__any(need)) {
#pragma unroll
      for (int mt = 0; mt < 2; ++mt)
#pragma unroll
        for (int i = 0; i < 4; ++i) {
          const float mnew = fmaxf(mrow[mt][i], pm[mt][i]);
          const float corr = exp2f((mrow[mt][i] - mnew) * c);
          mrow[mt][i] = mnew;
          lrow[mt][i] *= corr;
#pragma unroll
          for (int dt = 0; dt < 4; ++dt) oacc[mt][dt][i] *= corr;
        }
    }
    // P = exp2((S - m)*c), in place
#pragma unroll
    for (int mt = 0; mt < 2; ++mt)
#pragma unroll
      for (int n = 0; n < 4; ++n)
#pragma unroll
        for (int i = 0; i < 4; ++i)
          st[mt][n][i] = exp2f((st[mt][n][i] - mrow[mt][i]) * c);
#pragma unroll
    for (int mt = 0; mt < 2; ++mt)
#pragma unroll
      for (int i = 0; i < 4; ++i)
        lrow[mt][i] += (st[mt][0][i] + st[mt][1][i]) + (st[mt][2][i] + st[mt][3][i]);
    // P -> bf16 -> per-wave LDS strip (same-wave RAW)
#pragma unroll
    for (int mt = 0; mt < 2; ++mt)
#pragma unroll
      for (int n = 0; n < 4; ++n)
#pragma unroll
        for (int i = 0; i < 4; ++i)
          sP[w][mt * 16 + 4 * g + i][n * 16 + l15] = f2bf(st[mt][n][i]);
    s16x8 pf[2][2];
#pragma unroll
    for (int mt = 0; mt < 2; ++mt) {
      pf[mt][0] = *(const s16x8*)(&sP[w][mt * 16 + l15][g * 8]);
      pf[mt][1] = *(const s16x8*)(&sP[w][mt * 16 + l15][32 + g * 8]);
    }
    // PV: V-frag reads shared across both m-tiles
    __builtin_amdgcn_s_setprio(1);
#pragma unroll
    for (int dt = 0; dt < 4; ++dt) {
      s16x8 vf0 = ld_s16x8_a8(&sVt[dt * 16 + l15][g * 8]);
      s16x8 vf1 = ld_s16x8_a8(&sVt[dt * 16 + l15][32 + g * 8]);
#pragma unroll
      for (int mt = 0; mt < 2; ++mt) {
        oacc[mt][dt] = __builtin_amdgcn_mfma_f32_16x16x32_bf16(pf[mt][0], vf0, oacc[mt][dt], 0, 0, 0);
        oacc[mt][dt] = __builtin_amdgcn_mfma_f32_16x16x32_bf16(pf[mt][1], vf1, oacc[mt][dt], 0, 0, 0);
      }
    }
    __builtin_amdgcn_s_setprio(0);
  }

  // epilogue: reduce lrow across the 16-lane group, normalize, store
#pragma unroll
  for (int msk = 1; msk < 16; msk <<= 1)
#pragma unroll
    for (int mt = 0; mt < 2; ++mt)
#pragma unroll
      for (int i = 0; i < 4; ++i) lrow[mt][i] += __shfl_xor(lrow[mt][i], msk);
#pragma unroll
  for (int mt = 0; mt < 2; ++mt)
#pragma unroll
    for (int i = 0; i < 4; ++i) {
      const float inv = 1.f / lrow[mt][i];
      const size_t row = (size_t)(b * 2048 + qw + mt * 16 + 4 * g + i);
#pragma unroll
      for (int dt = 0; dt < 4; ++dt)
        o[row * 1024 + h * 64 + dt * 16 + l15] = f2bf(oacc[mt][dt][i] * inv);
    }
}

// ---------------------------------------------------------------------------
extern "C" void kernel_launch(void* const* d_in, const int* in_sizes, int n_in,
                              void* d_out, int out_size, void* d_ws, size_t ws_size,
                              hipStream_t stream) {
  const float* x     = (const float*)d_in[0];
  const float* Wq    = (const float*)d_in[1];
  const float* Wk    = (const float*)d_in[2];
  const float* Wv    = (const float*)d_in[3];
  const float* Wproj = (const float*)d_in[4];
  const float* bproj = (const float*)d_in[5];
  const float* W1    = (const float*)d_in[6];
  const float* b1    = (const float*)d_in[7];
  const float* W2    = (const float*)d_in[8];
  const float* b2    = (const float*)d_in[9];
  const float* g1    = (const float*)d_in[10];
  const float* be1   = (const float*)d_in[11];
  const float* g2    = (const float*)d_in[12];
  const float* be2   = (const float*)d_in[13];
  float* out = (float*)d_out;

  u16* WqkvT  = (u16*)d_ws;                    // [3072][1024] bf16
  u16* WprojT = WqkvT + (size_t)3072 * 1024;   // [1024][1024]
  u16* W1T    = WprojT + (size_t)1024 * 1024;  // [4096][1024]
  u16* W2T    = W1T + (size_t)4096 * 1024;     // [1024][4096]
  u16* hbuf   = W2T + (size_t)1024 * 4096;     // [4096][1024]
  u16* qkv    = hbuf + (size_t)4096 * 1024;    // [4096][3072]
  u16* obuf   = qkv + (size_t)4096 * 3072;     // [4096][1024]
  float* x2   = (float*)(obuf + (size_t)4096 * 1024);  // [4096][1024] fp32
  u16* a1     = (u16*)(x2 + (size_t)4096 * 1024);      // [4096][4096]

  transpose_f32_bf16<<<dim3(1, 16, 16), 256, 0, stream>>>(Wq, WqkvT,                      64, 65536, 65536, 1024);
  transpose_f32_bf16<<<dim3(1, 16, 16), 256, 0, stream>>>(Wk, WqkvT + (size_t)1024 * 1024, 64, 65536, 65536, 1024);
  transpose_f32_bf16<<<dim3(1, 16, 16), 256, 0, stream>>>(Wv, WqkvT + (size_t)2048 * 1024, 64, 65536, 65536, 1024);
  transpose_f32_bf16<<<dim3(16, 16, 1), 256, 0, stream>>>(Wproj, WprojT, 1024, 0, 0, 1024);
  transpose_f32_bf16<<<dim3(64, 16, 1), 256, 0, stream>>>(W1, W1T, 4096, 0, 0, 1024);
  transpose_f32_bf16<<<dim3(16, 64, 1), 256, 0, stream>>>(W2, W2T, 1024, 0, 0, 4096);

  ln_kernel<<<4096, 256, 0, stream>>>(x, g1, be1, hbuf);
  gemm_kernel<0, 128><<<dim3(24, 32), 256, 0, stream>>>(hbuf, WqkvT, nullptr, nullptr, qkv, 4096, 3072, 1024);
  attn_mfma_kernel<<<dim3(16, 32), 256, 0, stream>>>(qkv, obuf);
  gemm_kernel<2, 64><<<dim3(8, 64), 256, 0, stream>>>(obuf, WprojT, bproj, x, x2, 4096, 1024, 1024);
  ln_kernel<<<4096, 256, 0, stream>>>(x2, g2, be2, hbuf);
  gemm_kernel<1, 128><<<dim3(32, 32), 256, 0, stream>>>(hbuf, W1T, b1, nullptr, a1, 4096, 4096, 1024);
  gemm_kernel<2, 64><<<dim3(8, 64), 256, 0, stream>>>(a1, W2T, b2, x2, out, 4096, 1024, 4096);
}

// Round 10
// 293.887 us; speedup vs baseline: 1.0561x; 1.0561x over previous
//
#include <hip/hip_runtime.h>
#include <stdint.h>

// Round 10: attn = round-9 QBLK=128 structure + heavy-half-first 1-D grid
// (fixes round-9's tail imbalance: blocks 0..255 = qb 15..8, 256..511 =
// qb 7..0; light blocks backfill). GEMMs/LN/transposes frozen from round 8.

typedef unsigned short u16;
typedef unsigned int u32;
typedef __attribute__((ext_vector_type(4))) float f32x4;
typedef __attribute__((ext_vector_type(8))) short s16x8;

__device__ __forceinline__ u16 f2bf(float f) {
  u32 u = __builtin_bit_cast(u32, f);
  u += 0x7fffu + ((u >> 16) & 1u);
  return (u16)(u >> 16);
}
// 8-byte-aligned s16x8 load (2 x b64) for odd-stride LDS rows
__device__ __forceinline__ s16x8 ld_s16x8_a8(const u16* p) {
  union { uint2 d[2]; s16x8 v; } u;
  u.d[0] = *(const uint2*)p;
  u.d[1] = *(const uint2*)(p + 4);
  return u.v;
}
// async global->LDS, 16B per lane; lds dest must be wave-uniform base (lane*16 implicit)
__device__ __forceinline__ void gload16(const u16* g, u16* lds_base) {
  __builtin_amdgcn_global_load_lds(
      (const __attribute__((address_space(1))) void*)g,
      (__attribute__((address_space(3))) void*)lds_base, 16, 0, 0);
}

// ---------------------------------------------------------------------------
// Tiled transpose fp32 -> bf16: dst[(c)*dstStride + r] = src[r*Ccols + c]
// ---------------------------------------------------------------------------
__global__ __launch_bounds__(256) void transpose_f32_bf16(
    const float* __restrict__ src, u16* __restrict__ dst,
    int Ccols, long srcZ, long dstZ, int dstStride) {
  __shared__ float t[64][65];
  const float* s = src + (size_t)blockIdx.z * srcZ;
  u16* d = dst + (size_t)blockIdx.z * dstZ;
  const int r0 = blockIdx.y * 64, c0 = blockIdx.x * 64;
  const int tr = threadIdx.x >> 4, tc4 = (threadIdx.x & 15) * 4;
#pragma unroll
  for (int p = 0; p < 4; ++p) {
    int r = p * 16 + tr;
    float4 v = *(const float4*)(s + (size_t)(r0 + r) * Ccols + c0 + tc4);
    t[r][tc4 + 0] = v.x; t[r][tc4 + 1] = v.y;
    t[r][tc4 + 2] = v.z; t[r][tc4 + 3] = v.w;
  }
  __syncthreads();
#pragma unroll
  for (int p = 0; p < 4; ++p) {
    int c = p * 16 + tr;
    uint2 pk;
    pk.x = (u32)f2bf(t[tc4 + 0][c]) | ((u32)f2bf(t[tc4 + 1][c]) << 16);
    pk.y = (u32)f2bf(t[tc4 + 2][c]) | ((u32)f2bf(t[tc4 + 3][c]) << 16);
    *(uint2*)(d + (size_t)(c0 + c) * dstStride + r0 + tc4) = pk;
  }
}

// ---------------------------------------------------------------------------
// LayerNorm: one block per row of 1024 fp32; out bf16.
// ---------------------------------------------------------------------------
__global__ __launch_bounds__(256) void ln_kernel(
    const float* __restrict__ x, const float* __restrict__ g,
    const float* __restrict__ be, u16* __restrict__ out) {
  const int row = blockIdx.x, tid = threadIdx.x;
  const float* xr = x + (size_t)row * 1024;
  float4 v = *(const float4*)(xr + tid * 4);
  float s = v.x + v.y + v.z + v.w;
  float q = v.x * v.x + v.y * v.y + v.z * v.z + v.w * v.w;
#pragma unroll
  for (int off = 32; off > 0; off >>= 1) {
    s += __shfl_down(s, off);
    q += __shfl_down(q, off);
  }
  __shared__ float red[8];
  const int wid = tid >> 6, lane = tid & 63;
  if (lane == 0) { red[wid] = s; red[wid + 4] = q; }
  __syncthreads();
  s = red[0] + red[1] + red[2] + red[3];
  q = red[4] + red[5] + red[6] + red[7];
  const float mu = s * (1.f / 1024.f);
  const float var = q * (1.f / 1024.f) - mu * mu;
  const float rs = rsqrtf(var + 1e-5f);
  float4 gv = *(const float4*)(g + tid * 4);
  float4 bv = *(const float4*)(be + tid * 4);
  float o0 = (v.x - mu) * rs * gv.x + bv.x;
  float o1 = (v.y - mu) * rs * gv.y + bv.y;
  float o2 = (v.z - mu) * rs * gv.z + bv.z;
  float o3 = (v.w - mu) * rs * gv.w + bv.w;
  uint2 pk;
  pk.x = (u32)f2bf(o0) | ((u32)f2bf(o1) << 16);
  pk.y = (u32)f2bf(o2) | ((u32)f2bf(o3) << 16);
  *(uint2*)(out + (size_t)row * 1024 + tid * 4) = pk;
}

// ---------------------------------------------------------------------------
// GEMM: C[M,N] = A[M,K] @ BT[N,K]^T  (+ bias, relu, residual per EPI)
// EPI 0: -> bf16.  EPI 1: +bias, relu -> bf16.  EPI 2: +bias +resid -> fp32.
// BMx128 tile, BK=64, 256 threads (4 waves 2x2). m97 structure.
// ---------------------------------------------------------------------------
template <int EPI, int BM>
__global__ __launch_bounds__(256) void gemm_kernel(
    const u16* __restrict__ A, const u16* __restrict__ BT,
    const float* __restrict__ bias, const float* __restrict__ resid,
    void* __restrict__ out, int M, int N, int K) {
  __shared__ u16 sA[BM][64];
  __shared__ u16 sB[128][64];
  const int tid = threadIdx.x;
  const int m0 = blockIdx.y * BM, n0 = blockIdx.x * 128;
  const int wid = tid >> 6, lane = tid & 63;
  const int wr = (wid >> 1) * (BM / 2), wc = (wid & 1) * 64;
  const int l15 = lane & 15, g = lane >> 4;
  constexpr int MR = BM / 32;
  f32x4 acc[MR][4] = {};
  const int lr = lane >> 3;
  const int cswz = ((lane & 7) * 8) ^ (lr << 3);  // u16 units

  for (int k0 = 0; k0 < K; k0 += 64) {
    __syncthreads();
#pragma unroll
    for (int p = 0; p < MR; ++p) {
      const int row = (p * 4 + wid) * 8 + lr;  // row & 7 == lr
      gload16(A + (size_t)(m0 + row) * K + k0 + cswz, &sA[(p * 4 + wid) * 8][0]);
    }
#pragma unroll
    for (int p = 0; p < 4; ++p) {
      const int row = (p * 4 + wid) * 8 + lr;
      gload16(BT + (size_t)(n0 + row) * K + k0 + cswz, &sB[(p * 4 + wid) * 8][0]);
    }
    __syncthreads();  // drains vmcnt(0) before any ds_read
#pragma unroll
    for (int kk = 0; kk < 64; kk += 32) {
      s16x8 af[MR], bf[4];
#pragma unroll
      for (int m = 0; m < MR; ++m) {
        const int R = wr + m * 16 + l15;
        af[m] = *(const s16x8*)(&sA[R][(kk + g * 8) ^ ((R & 7) << 3)]);
      }
#pragma unroll
      for (int n = 0; n < 4; ++n) {
        const int R = wc + n * 16 + l15;
        bf[n] = *(const s16x8*)(&sB[R][(kk + g * 8) ^ ((R & 7) << 3)]);
      }
#pragma unroll
      for (int m = 0; m < MR; ++m)
#pragma unroll
        for (int n = 0; n < 4; ++n)
          acc[m][n] = __builtin_amdgcn_mfma_f32_16x16x32_bf16(af[m], bf[n], acc[m][n], 0, 0, 0);
    }
  }

#pragma unroll
  for (int m = 0; m < MR; ++m) {
#pragma unroll
    for (int n = 0; n < 4; ++n) {
      const int col = n0 + wc + n * 16 + l15;
      float bv = 0.f;
      if (EPI >= 1) bv = bias[col];
#pragma unroll
      for (int i = 0; i < 4; ++i) {
        const int row = m0 + wr + m * 16 + g * 4 + i;
        float v = acc[m][n][i];
        if (EPI >= 1) v += bv;
        if (EPI == 1) v = fmaxf(v, 0.f);
        if (EPI == 2) {
          v += resid[(size_t)row * N + col];
          ((float*)out)[(size_t)row * N + col] = v;
        } else {
          ((u16*)out)[(size_t)row * N + col] = f2bf(v);
        }
      }
    }
  }
}

// ---------------------------------------------------------------------------
// MFMA causal flash attention. QBLK=128, wave owns 32 q-rows (2 m-tiles).
// 1-D grid 512 blocks, heavy-half-first: lid<256 -> qb=15-(lid>>5)&7 (15..8),
// else qb=7-((lid-256)>>5) (7..0); bh = lid&31. T14 reg-prefetch; T13
// defer-max; T5 setprio.
// ---------------------------------------------------------------------------
__global__ __launch_bounds__(256) void attn_mfma_kernel(
    const u16* __restrict__ qkv, u16* __restrict__ o) {
  __shared__ u16 sK[64][72];     // [s][d]
  __shared__ u16 sVt[64][68];    // [d][s]
  __shared__ u16 sP[4][32][72];  // per-wave P strip [q][s]
  const int tid = threadIdx.x;
  const int lid = (int)blockIdx.x;
  const int bh = lid & 31;
  const int qb = (lid < 256) ? (15 - ((lid >> 5) & 7)) : (7 - ((lid - 256) >> 5));
  const int b = bh >> 4, h = bh & 15;
  const int w = tid >> 6, lane = tid & 63;
  const int l15 = lane & 15, g = lane >> 4;
  const float c = 0.125f * 1.4426950408889634f;  // scale * log2(e)
  const int ks_r = tid >> 2, ks_c = (tid & 3) * 16;
  const int vs_s = tid & 63, vs_d = (tid >> 6) * 8;
  const u16* kbase = qkv + (size_t)(b * 2048) * 3072 + 1024 + h * 64;
  const u16* vbase = kbase + 1024;
  const int qw = qb * 128 + w * 32;  // wave q base

  // Q fragments: 2 m-tiles x 2 k-halves (A-frag: row=l15, k=32*half+g*8+j)
  s16x8 qf[2][2];
#pragma unroll
  for (int mt = 0; mt < 2; ++mt) {
    const size_t qrow = (size_t)(b * 2048 + qw + mt * 16 + l15);
    qf[mt][0] = *(const s16x8*)(qkv + qrow * 3072 + h * 64 + g * 8);
    qf[mt][1] = *(const s16x8*)(qkv + qrow * 3072 + h * 64 + 32 + g * 8);
  }

  f32x4 oacc[2][4] = {};  // O[mt][dt]: row q=qw+mt*16+4g+i, col d=dt*16+l15
  float mrow[2][4], lrow[2][4];
#pragma unroll
  for (int mt = 0; mt < 2; ++mt)
#pragma unroll
    for (int i = 0; i < 4; ++i) { mrow[mt][i] = -1e30f; lrow[mt][i] = 0.f; }

  const int nt = 2 * qb + 2;
  // T14: prefetch tile 0 into regs
  uint4 kr0, kr1, vr0, vr1;
  {
    const u16* kp = kbase + (size_t)(ks_r)*3072 + ks_c;
    kr0 = *(const uint4*)kp; kr1 = *(const uint4*)(kp + 8);
    const u16* vp = vbase + (size_t)(vs_s)*3072 + vs_d;
    vr0 = *(const uint4*)vp; vr1 = *(const uint4*)(vp + 32);
  }
  for (int t = 0; t < nt; ++t) {
    __syncthreads();  // all waves done with previous tile's LDS
    *(uint4*)(&sK[ks_r][ks_c]) = kr0;
    *(uint4*)(&sK[ks_r][ks_c + 8]) = kr1;
    {
      union { uint4 q4; u16 e[8]; } va, vb;
      va.q4 = vr0; vb.q4 = vr1;
#pragma unroll
      for (int j = 0; j < 8; ++j) sVt[vs_d + j][vs_s] = va.e[j];
#pragma unroll
      for (int j = 0; j < 8; ++j) sVt[vs_d + 32 + j][vs_s] = vb.e[j];
    }
    __syncthreads();
    // issue next tile's global loads; latency hides under compute below
    if (t + 1 < nt) {
      const u16* kp = kbase + (size_t)((t + 1) * 64 + ks_r) * 3072 + ks_c;
      kr0 = *(const uint4*)kp; kr1 = *(const uint4*)(kp + 8);
      const u16* vp = vbase + (size_t)((t + 1) * 64 + vs_s) * 3072 + vs_d;
      vr0 = *(const uint4*)vp; vr1 = *(const uint4*)(vp + 32);
    }

    // QK^T: S[32 q][64 s]; K-frag reads shared across both m-tiles
    f32x4 st[2][4];
    __builtin_amdgcn_s_setprio(1);
#pragma unroll
    for (int n = 0; n < 4; ++n) {
      s16x8 k0 = *(const s16x8*)(&sK[n * 16 + l15][g * 8]);
      s16x8 k1 = *(const s16x8*)(&sK[n * 16 + l15][32 + g * 8]);
#pragma unroll
      for (int mt = 0; mt < 2; ++mt) {
        f32x4 a = {};
        a = __builtin_amdgcn_mfma_f32_16x16x32_bf16(qf[mt][0], k0, a, 0, 0, 0);
        a = __builtin_amdgcn_mfma_f32_16x16x32_bf16(qf[mt][1], k1, a, 0, 0, 0);
        st[mt][n] = a;
      }
    }
    __builtin_amdgcn_s_setprio(0);
    if (t >= 2 * qb) {  // causal mask (diagonal spans the last two tiles)
#pragma unroll
      for (int mt = 0; mt < 2; ++mt)
#pragma unroll
        for (int n = 0; n < 4; ++n)
#pragma unroll
          for (int i = 0; i < 4; ++i) {
            const int s_abs = t * 64 + n * 16 + l15;
            const int q_abs = qw + mt * 16 + 4 * g + i;
            if (s_abs > q_abs) st[mt][n][i] = -1e30f;
          }
    }
    // per-row max (reduce across the 16-lane group)
    float pm[2][4];
#pragma unroll
    for (int mt = 0; mt < 2; ++mt)
#pragma unroll
      for (int i = 0; i < 4; ++i)
        pm[mt][i] = fmaxf(fmaxf(st[mt][0][i], st[mt][1][i]),
                          fmaxf(st[mt][2][i], st[mt][3][i]));
#pragma unroll
    for (int msk = 1; msk < 16; msk <<= 1)
#pragma unroll
      for (int mt = 0; mt < 2; ++mt)
#pragma unroll
        for (int i = 0; i < 4; ++i) pm[mt][i] = fmaxf(pm[mt][i], __shfl_xor(pm[mt][i], msk));
    // T13 defer-max: only rescale when the tile max meaningfully exceeds mrow
    bool need = false;
#pragma unroll
    for (int mt = 0; mt < 2; ++mt)
#pragma unroll
      for (int i = 0; i < 4; ++i) need = need || (pm[mt][i] > mrow[mt][i] + 16.f);
    if (__any(need)) {
#pragma unroll
      for (int mt = 0; mt < 2; ++mt)
#pragma unroll
        for (int i = 0; i < 4; ++i) {
          const float mnew = fmaxf(mrow[mt][i], pm[mt][i]);
          const float corr = exp2f((mrow[mt][i] - mnew) * c);
          mrow[mt][i] = mnew;
          lrow[mt][i] *= corr;
#pragma unroll
          for (int dt = 0; dt < 4; ++dt) oacc[mt][dt][i] *= corr;
        }
    }
    // P = exp2((S - m)*c), in place
#pragma unroll
    for (int mt = 0; mt < 2; ++mt)
#pragma unroll
      for (int n = 0; n < 4; ++n)
#pragma unroll
        for (int i = 0; i < 4; ++i)
          st[mt][n][i] = exp2f((st[mt][n][i] - mrow[mt][i]) * c);
#pragma unroll
    for (int mt = 0; mt < 2; ++mt)
#pragma unroll
      for (int i = 0; i < 4; ++i)
        lrow[mt][i] += (st[mt][0][i] + st[mt][1][i]) + (st[mt][2][i] + st[mt][3][i]);
    // P -> bf16 -> per-wave LDS strip (same-wave RAW)
#pragma unroll
    for (int mt = 0; mt < 2; ++mt)
#pragma unroll
      for (int n = 0; n < 4; ++n)
#pragma unroll
        for (int i = 0; i < 4; ++i)
          sP[w][mt * 16 + 4 * g + i][n * 16 + l15] = f2bf(st[mt][n][i]);
    s16x8 pf[2][2];
#pragma unroll
    for (int mt = 0; mt < 2; ++mt) {
      pf[mt][0] = *(const s16x8*)(&sP[w][mt * 16 + l15][g * 8]);
      pf[mt][1] = *(const s16x8*)(&sP[w][mt * 16 + l15][32 + g * 8]);
    }
    // PV: V-frag reads shared across both m-tiles
    __builtin_amdgcn_s_setprio(1);
#pragma unroll
    for (int dt = 0; dt < 4; ++dt) {
      s16x8 vf0 = ld_s16x8_a8(&sVt[dt * 16 + l15][g * 8]);
      s16x8 vf1 = ld_s16x8_a8(&sVt[dt * 16 + l15][32 + g * 8]);
#pragma unroll
      for (int mt = 0; mt < 2; ++mt) {
        oacc[mt][dt] = __builtin_amdgcn_mfma_f32_16x16x32_bf16(pf[mt][0], vf0, oacc[mt][dt], 0, 0, 0);
        oacc[mt][dt] = __builtin_amdgcn_mfma_f32_16x16x32_bf16(pf[mt][1], vf1, oacc[mt][dt], 0, 0, 0);
      }
    }
    __builtin_amdgcn_s_setprio(0);
  }

  // epilogue: reduce lrow across the 16-lane group, normalize, store
#pragma unroll
  for (int msk = 1; msk < 16; msk <<= 1)
#pragma unroll
    for (int mt = 0; mt < 2; ++mt)
#pragma unroll
      for (int i = 0; i < 4; ++i) lrow[mt][i] += __shfl_xor(lrow[mt][i], msk);
#pragma unroll
  for (int mt = 0; mt < 2; ++mt)
#pragma unroll
    for (int i = 0; i < 4; ++i) {
      const float inv = 1.f / lrow[mt][i];
      const size_t row = (size_t)(b * 2048 + qw + mt * 16 + 4 * g + i);
#pragma unroll
      for (int dt = 0; dt < 4; ++dt)
        o[row * 1024 + h * 64 + dt * 16 + l15] = f2bf(oacc[mt][dt][i] * inv);
    }
}

// ---------------------------------------------------------------------------
extern "C" void kernel_launch(void* const* d_in, const int* in_sizes, int n_in,
                              void* d_out, int out_size, void* d_ws, size_t ws_size,
                              hipStream_t stream) {
  const float* x     = (const float*)d_in[0];
  const float* Wq    = (const float*)d_in[1];
  const float* Wk    = (const float*)d_in[2];
  const float* Wv    = (const float*)d_in[3];
  const float* Wproj = (const float*)d_in[4];
  const float* bproj = (const float*)d_in[5];
  const float* W1    = (const float*)d_in[6];
  const float* b1    = (const float*)d_in[7];
  const float* W2    = (const float*)d_in[8];
  const float* b2    = (const float*)d_in[9];
  const float* g1    = (const float*)d_in[10];
  const float* be1   = (const float*)d_in[11];
  const float* g2    = (const float*)d_in[12];
  const float* be2   = (const float*)d_in[13];
  float* out = (float*)d_out;

  u16* WqkvT  = (u16*)d_ws;                    // [3072][1024] bf16
  u16* WprojT = WqkvT + (size_t)3072 * 1024;   // [1024][1024]
  u16* W1T    = WprojT + (size_t)1024 * 1024;  // [4096][1024]
  u16* W2T    = W1T + (size_t)4096 * 1024;     // [1024][4096]
  u16* hbuf   = W2T + (size_t)1024 * 4096;     // [4096][1024]
  u16* qkv    = hbuf + (size_t)4096 * 1024;    // [4096][3072]
  u16* obuf   = qkv + (size_t)4096 * 3072;     // [4096][1024]
  float* x2   = (float*)(obuf + (size_t)4096 * 1024);  // [4096][1024] fp32
  u16* a1     = (u16*)(x2 + (size_t)4096 * 1024);      // [4096][4096]

  transpose_f32_bf16<<<dim3(1, 16, 16), 256, 0, stream>>>(Wq, WqkvT,                      64, 65536, 65536, 1024);
  transpose_f32_bf16<<<dim3(1, 16, 16), 256, 0, stream>>>(Wk, WqkvT + (size_t)1024 * 1024, 64, 65536, 65536, 1024);
  transpose_f32_bf16<<<dim3(1, 16, 16), 256, 0, stream>>>(Wv, WqkvT + (size_t)2048 * 1024, 64, 65536, 65536, 1024);
  transpose_f32_bf16<<<dim3(16, 16, 1), 256, 0, stream>>>(Wproj, WprojT, 1024, 0, 0, 1024);
  transpose_f32_bf16<<<dim3(64, 16, 1), 256, 0, stream>>>(W1, W1T, 4096, 0, 0, 1024);
  transpose_f32_bf16<<<dim3(16, 64, 1), 256, 0, stream>>>(W2, W2T, 1024, 0, 0, 4096);

  ln_kernel<<<4096, 256, 0, stream>>>(x, g1, be1, hbuf);
  gemm_kernel<0, 128><<<dim3(24, 32), 256, 0, stream>>>(hbuf, WqkvT, nullptr, nullptr, qkv, 4096, 3072, 1024);
  attn_mfma_kernel<<<512, 256, 0, stream>>>(qkv, obuf);
  gemm_kernel<2, 64><<<dim3(8, 64), 256, 0, stream>>>(obuf, WprojT, bproj, x, x2, 4096, 1024, 1024);
  ln_kernel<<<4096, 256, 0, stream>>>(x2, g2, be2, hbuf);
  gemm_kernel<1, 128><<<dim3(32, 32), 256, 0, stream>>>(hbuf, W1T, b1, nullptr, a1, 4096, 4096, 1024);
  gemm_kernel<2, 64><<<dim3(8, 64), 256, 0, stream>>>(a1, W2T, b2, x2, out, 4096, 1024, 4096);
}

// Round 11
// 290.210 us; speedup vs baseline: 1.0695x; 1.0127x over previous
//
#include <hip/hip_runtime.h>
#include <stdint.h>

// Round 11: one-line fix of round-10's block->qb mapping. All 512 attn blocks
// are co-resident (VGPR/LDS allow 4 blocks/CU), so there is NO backfill; the
// makespan is the worst per-CU SUM of its two resident blocks. Under round-
// robin placement lid and lid+256 share a CU, so the light half must be
// ASCENDING to anti-correlate: block c -> qb=15-(c>>5), block 256+c ->
// qb=(c>>5); per-CU tiles = (2(15-x)+2)+(2x+2) = 34, uniform.
// GEMMs/LN/transposes frozen from round 8.

typedef unsigned short u16;
typedef unsigned int u32;
typedef __attribute__((ext_vector_type(4))) float f32x4;
typedef __attribute__((ext_vector_type(8))) short s16x8;

__device__ __forceinline__ u16 f2bf(float f) {
  u32 u = __builtin_bit_cast(u32, f);
  u += 0x7fffu + ((u >> 16) & 1u);
  return (u16)(u >> 16);
}
// 8-byte-aligned s16x8 load (2 x b64) for odd-stride LDS rows
__device__ __forceinline__ s16x8 ld_s16x8_a8(const u16* p) {
  union { uint2 d[2]; s16x8 v; } u;
  u.d[0] = *(const uint2*)p;
  u.d[1] = *(const uint2*)(p + 4);
  return u.v;
}
// async global->LDS, 16B per lane; lds dest must be wave-uniform base (lane*16 implicit)
__device__ __forceinline__ void gload16(const u16* g, u16* lds_base) {
  __builtin_amdgcn_global_load_lds(
      (const __attribute__((address_space(1))) void*)g,
      (__attribute__((address_space(3))) void*)lds_base, 16, 0, 0);
}

// ---------------------------------------------------------------------------
// Tiled transpose fp32 -> bf16: dst[(c)*dstStride + r] = src[r*Ccols + c]
// ---------------------------------------------------------------------------
__global__ __launch_bounds__(256) void transpose_f32_bf16(
    const float* __restrict__ src, u16* __restrict__ dst,
    int Ccols, long srcZ, long dstZ, int dstStride) {
  __shared__ float t[64][65];
  const float* s = src + (size_t)blockIdx.z * srcZ;
  u16* d = dst + (size_t)blockIdx.z * dstZ;
  const int r0 = blockIdx.y * 64, c0 = blockIdx.x * 64;
  const int tr = threadIdx.x >> 4, tc4 = (threadIdx.x & 15) * 4;
#pragma unroll
  for (int p = 0; p < 4; ++p) {
    int r = p * 16 + tr;
    float4 v = *(const float4*)(s + (size_t)(r0 + r) * Ccols + c0 + tc4);
    t[r][tc4 + 0] = v.x; t[r][tc4 + 1] = v.y;
    t[r][tc4 + 2] = v.z; t[r][tc4 + 3] = v.w;
  }
  __syncthreads();
#pragma unroll
  for (int p = 0; p < 4; ++p) {
    int c = p * 16 + tr;
    uint2 pk;
    pk.x = (u32)f2bf(t[tc4 + 0][c]) | ((u32)f2bf(t[tc4 + 1][c]) << 16);
    pk.y = (u32)f2bf(t[tc4 + 2][c]) | ((u32)f2bf(t[tc4 + 3][c]) << 16);
    *(uint2*)(d + (size_t)(c0 + c) * dstStride + r0 + tc4) = pk;
  }
}

// ---------------------------------------------------------------------------
// LayerNorm: one block per row of 1024 fp32; out bf16.
// ---------------------------------------------------------------------------
__global__ __launch_bounds__(256) void ln_kernel(
    const float* __restrict__ x, const float* __restrict__ g,
    const float* __restrict__ be, u16* __restrict__ out) {
  const int row = blockIdx.x, tid = threadIdx.x;
  const float* xr = x + (size_t)row * 1024;
  float4 v = *(const float4*)(xr + tid * 4);
  float s = v.x + v.y + v.z + v.w;
  float q = v.x * v.x + v.y * v.y + v.z * v.z + v.w * v.w;
#pragma unroll
  for (int off = 32; off > 0; off >>= 1) {
    s += __shfl_down(s, off);
    q += __shfl_down(q, off);
  }
  __shared__ float red[8];
  const int wid = tid >> 6, lane = tid & 63;
  if (lane == 0) { red[wid] = s; red[wid + 4] = q; }
  __syncthreads();
  s = red[0] + red[1] + red[2] + red[3];
  q = red[4] + red[5] + red[6] + red[7];
  const float mu = s * (1.f / 1024.f);
  const float var = q * (1.f / 1024.f) - mu * mu;
  const float rs = rsqrtf(var + 1e-5f);
  float4 gv = *(const float4*)(g + tid * 4);
  float4 bv = *(const float4*)(be + tid * 4);
  float o0 = (v.x - mu) * rs * gv.x + bv.x;
  float o1 = (v.y - mu) * rs * gv.y + bv.y;
  float o2 = (v.z - mu) * rs * gv.z + bv.z;
  float o3 = (v.w - mu) * rs * gv.w + bv.w;
  uint2 pk;
  pk.x = (u32)f2bf(o0) | ((u32)f2bf(o1) << 16);
  pk.y = (u32)f2bf(o2) | ((u32)f2bf(o3) << 16);
  *(uint2*)(out + (size_t)row * 1024 + tid * 4) = pk;
}

// ---------------------------------------------------------------------------
// GEMM: C[M,N] = A[M,K] @ BT[N,K]^T  (+ bias, relu, residual per EPI)
// EPI 0: -> bf16.  EPI 1: +bias, relu -> bf16.  EPI 2: +bias +resid -> fp32.
// BMx128 tile, BK=64, 256 threads (4 waves 2x2). m97 structure.
// ---------------------------------------------------------------------------
template <int EPI, int BM>
__global__ __launch_bounds__(256) void gemm_kernel(
    const u16* __restrict__ A, const u16* __restrict__ BT,
    const float* __restrict__ bias, const float* __restrict__ resid,
    void* __restrict__ out, int M, int N, int K) {
  __shared__ u16 sA[BM][64];
  __shared__ u16 sB[128][64];
  const int tid = threadIdx.x;
  const int m0 = blockIdx.y * BM, n0 = blockIdx.x * 128;
  const int wid = tid >> 6, lane = tid & 63;
  const int wr = (wid >> 1) * (BM / 2), wc = (wid & 1) * 64;
  const int l15 = lane & 15, g = lane >> 4;
  constexpr int MR = BM / 32;
  f32x4 acc[MR][4] = {};
  const int lr = lane >> 3;
  const int cswz = ((lane & 7) * 8) ^ (lr << 3);  // u16 units

  for (int k0 = 0; k0 < K; k0 += 64) {
    __syncthreads();
#pragma unroll
    for (int p = 0; p < MR; ++p) {
      const int row = (p * 4 + wid) * 8 + lr;  // row & 7 == lr
      gload16(A + (size_t)(m0 + row) * K + k0 + cswz, &sA[(p * 4 + wid) * 8][0]);
    }
#pragma unroll
    for (int p = 0; p < 4; ++p) {
      const int row = (p * 4 + wid) * 8 + lr;
      gload16(BT + (size_t)(n0 + row) * K + k0 + cswz, &sB[(p * 4 + wid) * 8][0]);
    }
    __syncthreads();  // drains vmcnt(0) before any ds_read
#pragma unroll
    for (int kk = 0; kk < 64; kk += 32) {
      s16x8 af[MR], bf[4];
#pragma unroll
      for (int m = 0; m < MR; ++m) {
        const int R = wr + m * 16 + l15;
        af[m] = *(const s16x8*)(&sA[R][(kk + g * 8) ^ ((R & 7) << 3)]);
      }
#pragma unroll
      for (int n = 0; n < 4; ++n) {
        const int R = wc + n * 16 + l15;
        bf[n] = *(const s16x8*)(&sB[R][(kk + g * 8) ^ ((R & 7) << 3)]);
      }
#pragma unroll
      for (int m = 0; m < MR; ++m)
#pragma unroll
        for (int n = 0; n < 4; ++n)
          acc[m][n] = __builtin_amdgcn_mfma_f32_16x16x32_bf16(af[m], bf[n], acc[m][n], 0, 0, 0);
    }
  }

#pragma unroll
  for (int m = 0; m < MR; ++m) {
#pragma unroll
    for (int n = 0; n < 4; ++n) {
      const int col = n0 + wc + n * 16 + l15;
      float bv = 0.f;
      if (EPI >= 1) bv = bias[col];
#pragma unroll
      for (int i = 0; i < 4; ++i) {
        const int row = m0 + wr + m * 16 + g * 4 + i;
        float v = acc[m][n][i];
        if (EPI >= 1) v += bv;
        if (EPI == 1) v = fmaxf(v, 0.f);
        if (EPI == 2) {
          v += resid[(size_t)row * N + col];
          ((float*)out)[(size_t)row * N + col] = v;
        } else {
          ((u16*)out)[(size_t)row * N + col] = f2bf(v);
        }
      }
    }
  }
}

// ---------------------------------------------------------------------------
// MFMA causal flash attention. QBLK=128, wave owns 32 q-rows (2 m-tiles).
// 1-D grid 512 blocks: lid<256 -> qb=15-((lid>>5)&7); lid>=256 ->
// qb=(lid-256)>>5 (ASCENDING, anti-correlated with same-CU heavy partner).
// T14 reg-prefetch; T13 defer-max; T5 setprio.
// ---------------------------------------------------------------------------
__global__ __launch_bounds__(256) void attn_mfma_kernel(
    const u16* __restrict__ qkv, u16* __restrict__ o) {
  __shared__ u16 sK[64][72];     // [s][d]
  __shared__ u16 sVt[64][68];    // [d][s]
  __shared__ u16 sP[4][32][72];  // per-wave P strip [q][s]
  const int tid = threadIdx.x;
  const int lid = (int)blockIdx.x;
  const int bh = lid & 31;
  const int qb = (lid < 256) ? (15 - ((lid >> 5) & 7)) : ((lid - 256) >> 5);
  const int b = bh >> 4, h = bh & 15;
  const int w = tid >> 6, lane = tid & 63;
  const int l15 = lane & 15, g = lane >> 4;
  const float c = 0.125f * 1.4426950408889634f;  // scale * log2(e)
  const int ks_r = tid >> 2, ks_c = (tid & 3) * 16;
  const int vs_s = tid & 63, vs_d = (tid >> 6) * 8;
  const u16* kbase = qkv + (size_t)(b * 2048) * 3072 + 1024 + h * 64;
  const u16* vbase = kbase + 1024;
  const int qw = qb * 128 + w * 32;  // wave q base

  // Q fragments: 2 m-tiles x 2 k-halves (A-frag: row=l15, k=32*half+g*8+j)
  s16x8 qf[2][2];
#pragma unroll
  for (int mt = 0; mt < 2; ++mt) {
    const size_t qrow = (size_t)(b * 2048 + qw + mt * 16 + l15);
    qf[mt][0] = *(const s16x8*)(qkv + qrow * 3072 + h * 64 + g * 8);
    qf[mt][1] = *(const s16x8*)(qkv + qrow * 3072 + h * 64 + 32 + g * 8);
  }

  f32x4 oacc[2][4] = {};  // O[mt][dt]: row q=qw+mt*16+4g+i, col d=dt*16+l15
  float mrow[2][4], lrow[2][4];
#pragma unroll
  for (int mt = 0; mt < 2; ++mt)
#pragma unroll
    for (int i = 0; i < 4; ++i) { mrow[mt][i] = -1e30f; lrow[mt][i] = 0.f; }

  const int nt = 2 * qb + 2;
  // T14: prefetch tile 0 into regs
  uint4 kr0, kr1, vr0, vr1;
  {
    const u16* kp = kbase + (size_t)(ks_r)*3072 + ks_c;
    kr0 = *(const uint4*)kp; kr1 = *(const uint4*)(kp + 8);
    const u16* vp = vbase + (size_t)(vs_s)*3072 + vs_d;
    vr0 = *(const uint4*)vp; vr1 = *(const uint4*)(vp + 32);
  }
  for (int t = 0; t < nt; ++t) {
    __syncthreads();  // all waves done with previous tile's LDS
    *(uint4*)(&sK[ks_r][ks_c]) = kr0;
    *(uint4*)(&sK[ks_r][ks_c + 8]) = kr1;
    {
      union { uint4 q4; u16 e[8]; } va, vb;
      va.q4 = vr0; vb.q4 = vr1;
#pragma unroll
      for (int j = 0; j < 8; ++j) sVt[vs_d + j][vs_s] = va.e[j];
#pragma unroll
      for (int j = 0; j < 8; ++j) sVt[vs_d + 32 + j][vs_s] = vb.e[j];
    }
    __syncthreads();
    // issue next tile's global loads; latency hides under compute below
    if (t + 1 < nt) {
      const u16* kp = kbase + (size_t)((t + 1) * 64 + ks_r) * 3072 + ks_c;
      kr0 = *(const uint4*)kp; kr1 = *(const uint4*)(kp + 8);
      const u16* vp = vbase + (size_t)((t + 1) * 64 + vs_s) * 3072 + vs_d;
      vr0 = *(const uint4*)vp; vr1 = *(const uint4*)(vp + 32);
    }

    // QK^T: S[32 q][64 s]; K-frag reads shared across both m-tiles
    f32x4 st[2][4];
    __builtin_amdgcn_s_setprio(1);
#pragma unroll
    for (int n = 0; n < 4; ++n) {
      s16x8 k0 = *(const s16x8*)(&sK[n * 16 + l15][g * 8]);
      s16x8 k1 = *(const s16x8*)(&sK[n * 16 + l15][32 + g * 8]);
#pragma unroll
      for (int mt = 0; mt < 2; ++mt) {
        f32x4 a = {};
        a = __builtin_amdgcn_mfma_f32_16x16x32_bf16(qf[mt][0], k0, a, 0, 0, 0);
        a = __builtin_amdgcn_mfma_f32_16x16x32_bf16(qf[mt][1], k1, a, 0, 0, 0);
        st[mt][n] = a;
      }
    }
    __builtin_amdgcn_s_setprio(0);
    if (t >= 2 * qb) {  // causal mask (diagonal spans the last two tiles)
#pragma unroll
      for (int mt = 0; mt < 2; ++mt)
#pragma unroll
        for (int n = 0; n < 4; ++n)
#pragma unroll
          for (int i = 0; i < 4; ++i) {
            const int s_abs = t * 64 + n * 16 + l15;
            const int q_abs = qw + mt * 16 + 4 * g + i;
            if (s_abs > q_abs) st[mt][n][i] = -1e30f;
          }
    }
    // per-row max (reduce across the 16-lane group)
    float pm[2][4];
#pragma unroll
    for (int mt = 0; mt < 2; ++mt)
#pragma unroll
      for (int i = 0; i < 4; ++i)
        pm[mt][i] = fmaxf(fmaxf(st[mt][0][i], st[mt][1][i]),
                          fmaxf(st[mt][2][i], st[mt][3][i]));
#pragma unroll
    for (int msk = 1; msk < 16; msk <<= 1)
#pragma unroll
      for (int mt = 0; mt < 2; ++mt)
#pragma unroll
        for (int i = 0; i < 4; ++i) pm[mt][i] = fmaxf(pm[mt][i], __shfl_xor(pm[mt][i], msk));
    // T13 defer-max: only rescale when the tile max meaningfully exceeds mrow
    bool need = false;
#pragma unroll
    for (int mt = 0; mt < 2; ++mt)
#pragma unroll
      for (int i = 0; i < 4; ++i) need = need || (pm[mt][i] > mrow[mt][i] + 16.f);
    if (__any(need)) {
#pragma unroll
      for (int mt = 0; mt < 2; ++mt)
#pragma unroll
        for (int i = 0; i < 4; ++i) {
          const float mnew = fmaxf(mrow[mt][i], pm[mt][i]);
          const float corr = exp2f((mrow[mt][i] - mnew) * c);
          mrow[mt][i] = mnew;
          lrow[mt][i] *= corr;
#pragma unroll
          for (int dt = 0; dt < 4; ++dt) oacc[mt][dt][i] *= corr;
        }
    }
    // P = exp2((S - m)*c), in place
#pragma unroll
    for (int mt = 0; mt < 2; ++mt)
#pragma unroll
      for (int n = 0; n < 4; ++n)
#pragma unroll
        for (int i = 0; i < 4; ++i)
          st[mt][n][i] = exp2f((st[mt][n][i] - mrow[mt][i]) * c);
#pragma unroll
    for (int mt = 0; mt < 2; ++mt)
#pragma unroll
      for (int i = 0; i < 4; ++i)
        lrow[mt][i] += (st[mt][0][i] + st[mt][1][i]) + (st[mt][2][i] + st[mt][3][i]);
    // P -> bf16 -> per-wave LDS strip (same-wave RAW)
#pragma unroll
    for (int mt = 0; mt < 2; ++mt)
#pragma unroll
      for (int n = 0; n < 4; ++n)
#pragma unroll
        for (int i = 0; i < 4; ++i)
          sP[w][mt * 16 + 4 * g + i][n * 16 + l15] = f2bf(st[mt][n][i]);
    s16x8 pf[2][2];
#pragma unroll
    for (int mt = 0; mt < 2; ++mt) {
      pf[mt][0] = *(const s16x8*)(&sP[w][mt * 16 + l15][g * 8]);
      pf[mt][1] = *(const s16x8*)(&sP[w][mt * 16 + l15][32 + g * 8]);
    }
    // PV: V-frag reads shared across both m-tiles
    __builtin_amdgcn_s_setprio(1);
#pragma unroll
    for (int dt = 0; dt < 4; ++dt) {
      s16x8 vf0 = ld_s16x8_a8(&sVt[dt * 16 + l15][g * 8]);
      s16x8 vf1 = ld_s16x8_a8(&sVt[dt * 16 + l15][32 + g * 8]);
#pragma unroll
      for (int mt = 0; mt < 2; ++mt) {
        oacc[mt][dt] = __builtin_amdgcn_mfma_f32_16x16x32_bf16(pf[mt][0], vf0, oacc[mt][dt], 0, 0, 0);
        oacc[mt][dt] = __builtin_amdgcn_mfma_f32_16x16x32_bf16(pf[mt][1], vf1, oacc[mt][dt], 0, 0, 0);
      }
    }
    __builtin_amdgcn_s_setprio(0);
  }

  // epilogue: reduce lrow across the 16-lane group, normalize, store
#pragma unroll
  for (int msk = 1; msk < 16; msk <<= 1)
#pragma unroll
    for (int mt = 0; mt < 2; ++mt)
#pragma unroll
      for (int i = 0; i < 4; ++i) lrow[mt][i] += __shfl_xor(lrow[mt][i], msk);
#pragma unroll
  for (int mt = 0; mt < 2; ++mt)
#pragma unroll
    for (int i = 0; i < 4; ++i) {
      const float inv = 1.f / lrow[mt][i];
      const size_t row = (size_t)(b * 2048 + qw + mt * 16 + 4 * g + i);
#pragma unroll
      for (int dt = 0; dt < 4; ++dt)
        o[row * 1024 + h * 64 + dt * 16 + l15] = f2bf(oacc[mt][dt][i] * inv);
    }
}

// ---------------------------------------------------------------------------
extern "C" void kernel_launch(void* const* d_in, const int* in_sizes, int n_in,
                              void* d_out, int out_size, void* d_ws, size_t ws_size,
                              hipStream_t stream) {
  const float* x     = (const float*)d_in[0];
  const float* Wq    = (const float*)d_in[1];
  const float* Wk    = (const float*)d_in[2];
  const float* Wv    = (const float*)d_in[3];
  const float* Wproj = (const float*)d_in[4];
  const float* bproj = (const float*)d_in[5];
  const float* W1    = (const float*)d_in[6];
  const float* b1    = (const float*)d_in[7];
  const float* W2    = (const float*)d_in[8];
  const float* b2    = (const float*)d_in[9];
  const float* g1    = (const float*)d_in[10];
  const float* be1   = (const float*)d_in[11];
  const float* g2    = (const float*)d_in[12];
  const float* be2   = (const float*)d_in[13];
  float* out = (float*)d_out;

  u16* WqkvT  = (u16*)d_ws;                    // [3072][1024] bf16
  u16* WprojT = WqkvT + (size_t)3072 * 1024;   // [1024][1024]
  u16* W1T    = WprojT + (size_t)1024 * 1024;  // [4096][1024]
  u16* W2T    = W1T + (size_t)4096 * 1024;     // [1024][4096]
  u16* hbuf   = W2T + (size_t)1024 * 4096;     // [4096][1024]
  u16* qkv    = hbuf + (size_t)4096 * 1024;    // [4096][3072]
  u16* obuf   = qkv + (size_t)4096 * 3072;     // [4096][1024]
  float* x2   = (float*)(obuf + (size_t)4096 * 1024);  // [4096][1024] fp32
  u16* a1     = (u16*)(x2 + (size_t)4096 * 1024);      // [4096][4096]

  transpose_f32_bf16<<<dim3(1, 16, 16), 256, 0, stream>>>(Wq, WqkvT,                      64, 65536, 65536, 1024);
  transpose_f32_bf16<<<dim3(1, 16, 16), 256, 0, stream>>>(Wk, WqkvT + (size_t)1024 * 1024, 64, 65536, 65536, 1024);
  transpose_f32_bf16<<<dim3(1, 16, 16), 256, 0, stream>>>(Wv, WqkvT + (size_t)2048 * 1024, 64, 65536, 65536, 1024);
  transpose_f32_bf16<<<dim3(16, 16, 1), 256, 0, stream>>>(Wproj, WprojT, 1024, 0, 0, 1024);
  transpose_f32_bf16<<<dim3(64, 16, 1), 256, 0, stream>>>(W1, W1T, 4096, 0, 0, 1024);
  transpose_f32_bf16<<<dim3(16, 64, 1), 256, 0, stream>>>(W2, W2T, 1024, 0, 0, 4096);

  ln_kernel<<<4096, 256, 0, stream>>>(x, g1, be1, hbuf);
  gemm_kernel<0, 128><<<dim3(24, 32), 256, 0, stream>>>(hbuf, WqkvT, nullptr, nullptr, qkv, 4096, 3072, 1024);
  attn_mfma_kernel<<<512, 256, 0, stream>>>(qkv, obuf);
  gemm_kernel<2, 64><<<dim3(8, 64), 256, 0, stream>>>(obuf, WprojT, bproj, x, x2, 4096, 1024, 1024);
  ln_kernel<<<4096, 256, 0, stream>>>(x2, g2, be2, hbuf);
  gemm_kernel<1, 128><<<dim3(32, 32), 256, 0, stream>>>(hbuf, W1T, b1, nullptr, a1, 4096, 4096, 1024);
  gemm_kernel<2, 64><<<dim3(8, 64), 256, 0, stream>>>(a1, W2T, b2, x2, out, 4096, 1024, 4096);
}

// Round 12
// 272.313 us; speedup vs baseline: 1.1398x; 1.0657x over previous
//
#include <hip/hip_runtime.h>
#include <stdint.h>

// Round 12: (a) attn reverted to round-8 exact code (known 81.6 us; the
// QBLK=128 line r9-r11 never beat it). (b) FF1 ported to a 256x256 8-phase
// double-buffered schedule (T3+T4+T5, guide section 5): 8 waves, 2 K-tiles
// per iteration, per-phase {ds_read quadrant | issue 1 half-tile -> barrier
// -> lgkmcnt(0) -> 16 MFMA -> barrier}, vmcnt(0) only at phases 4/8 (lands
// ~4 phases after issue). QKV/proj/FF2/LN/transposes frozen (m97 structure).

typedef unsigned short u16;
typedef unsigned int u32;
typedef __attribute__((ext_vector_type(4))) float f32x4;
typedef __attribute__((ext_vector_type(8))) short s16x8;

__device__ __forceinline__ u16 f2bf(float f) {
  u32 u = __builtin_bit_cast(u32, f);
  u += 0x7fffu + ((u >> 16) & 1u);
  return (u16)(u >> 16);
}
// 8-byte-aligned s16x8 load (2 x b64) for odd-stride LDS rows
__device__ __forceinline__ s16x8 ld_s16x8_a8(const u16* p) {
  union { uint2 d[2]; s16x8 v; } u;
  u.d[0] = *(const uint2*)p;
  u.d[1] = *(const uint2*)(p + 4);
  return u.v;
}
// async global->LDS, 16B per lane; lds dest must be wave-uniform base
__device__ __forceinline__ void gload16(const u16* g, u16* lds_base) {
  __builtin_amdgcn_global_load_lds(
      (const __attribute__((address_space(1))) void*)g,
      (__attribute__((address_space(3))) void*)lds_base, 16, 0, 0);
}

// ---------------------------------------------------------------------------
// Tiled transpose fp32 -> bf16: dst[(c)*dstStride + r] = src[r*Ccols + c]
// ---------------------------------------------------------------------------
__global__ __launch_bounds__(256) void transpose_f32_bf16(
    const float* __restrict__ src, u16* __restrict__ dst,
    int Ccols, long srcZ, long dstZ, int dstStride) {
  __shared__ float t[64][65];
  const float* s = src + (size_t)blockIdx.z * srcZ;
  u16* d = dst + (size_t)blockIdx.z * dstZ;
  const int r0 = blockIdx.y * 64, c0 = blockIdx.x * 64;
  const int tr = threadIdx.x >> 4, tc4 = (threadIdx.x & 15) * 4;
#pragma unroll
  for (int p = 0; p < 4; ++p) {
    int r = p * 16 + tr;
    float4 v = *(const float4*)(s + (size_t)(r0 + r) * Ccols + c0 + tc4);
    t[r][tc4 + 0] = v.x; t[r][tc4 + 1] = v.y;
    t[r][tc4 + 2] = v.z; t[r][tc4 + 3] = v.w;
  }
  __syncthreads();
#pragma unroll
  for (int p = 0; p < 4; ++p) {
    int c = p * 16 + tr;
    uint2 pk;
    pk.x = (u32)f2bf(t[tc4 + 0][c]) | ((u32)f2bf(t[tc4 + 1][c]) << 16);
    pk.y = (u32)f2bf(t[tc4 + 2][c]) | ((u32)f2bf(t[tc4 + 3][c]) << 16);
    *(uint2*)(d + (size_t)(c0 + c) * dstStride + r0 + tc4) = pk;
  }
}

// ---------------------------------------------------------------------------
// LayerNorm: one block per row of 1024 fp32; out bf16.
// ---------------------------------------------------------------------------
__global__ __launch_bounds__(256) void ln_kernel(
    const float* __restrict__ x, const float* __restrict__ g,
    const float* __restrict__ be, u16* __restrict__ out) {
  const int row = blockIdx.x, tid = threadIdx.x;
  const float* xr = x + (size_t)row * 1024;
  float4 v = *(const float4*)(xr + tid * 4);
  float s = v.x + v.y + v.z + v.w;
  float q = v.x * v.x + v.y * v.y + v.z * v.z + v.w * v.w;
#pragma unroll
  for (int off = 32; off > 0; off >>= 1) {
    s += __shfl_down(s, off);
    q += __shfl_down(q, off);
  }
  __shared__ float red[8];
  const int wid = tid >> 6, lane = tid & 63;
  if (lane == 0) { red[wid] = s; red[wid + 4] = q; }
  __syncthreads();
  s = red[0] + red[1] + red[2] + red[3];
  q = red[4] + red[5] + red[6] + red[7];
  const float mu = s * (1.f / 1024.f);
  const float var = q * (1.f / 1024.f) - mu * mu;
  const float rs = rsqrtf(var + 1e-5f);
  float4 gv = *(const float4*)(g + tid * 4);
  float4 bv = *(const float4*)(be + tid * 4);
  float o0 = (v.x - mu) * rs * gv.x + bv.x;
  float o1 = (v.y - mu) * rs * gv.y + bv.y;
  float o2 = (v.z - mu) * rs * gv.z + bv.z;
  float o3 = (v.w - mu) * rs * gv.w + bv.w;
  uint2 pk;
  pk.x = (u32)f2bf(o0) | ((u32)f2bf(o1) << 16);
  pk.y = (u32)f2bf(o2) | ((u32)f2bf(o3) << 16);
  *(uint2*)(out + (size_t)row * 1024 + tid * 4) = pk;
}

// ---------------------------------------------------------------------------
// GEMM (m97): C[M,N] = A[M,K] @ BT[N,K]^T (+ bias, relu, residual per EPI)
// ---------------------------------------------------------------------------
template <int EPI, int BM>
__global__ __launch_bounds__(256) void gemm_kernel(
    const u16* __restrict__ A, const u16* __restrict__ BT,
    const float* __restrict__ bias, const float* __restrict__ resid,
    void* __restrict__ out, int M, int N, int K) {
  __shared__ u16 sA[BM][64];
  __shared__ u16 sB[128][64];
  const int tid = threadIdx.x;
  const int m0 = blockIdx.y * BM, n0 = blockIdx.x * 128;
  const int wid = tid >> 6, lane = tid & 63;
  const int wr = (wid >> 1) * (BM / 2), wc = (wid & 1) * 64;
  const int l15 = lane & 15, g = lane >> 4;
  constexpr int MR = BM / 32;
  f32x4 acc[MR][4] = {};
  const int lr = lane >> 3;
  const int cswz = ((lane & 7) * 8) ^ (lr << 3);  // u16 units

  for (int k0 = 0; k0 < K; k0 += 64) {
    __syncthreads();
#pragma unroll
    for (int p = 0; p < MR; ++p) {
      const int row = (p * 4 + wid) * 8 + lr;
      gload16(A + (size_t)(m0 + row) * K + k0 + cswz, &sA[(p * 4 + wid) * 8][0]);
    }
#pragma unroll
    for (int p = 0; p < 4; ++p) {
      const int row = (p * 4 + wid) * 8 + lr;
      gload16(BT + (size_t)(n0 + row) * K + k0 + cswz, &sB[(p * 4 + wid) * 8][0]);
    }
    __syncthreads();
#pragma unroll
    for (int kk = 0; kk < 64; kk += 32) {
      s16x8 af[MR], bf[4];
#pragma unroll
      for (int m = 0; m < MR; ++m) {
        const int R = wr + m * 16 + l15;
        af[m] = *(const s16x8*)(&sA[R][(kk + g * 8) ^ ((R & 7) << 3)]);
      }
#pragma unroll
      for (int n = 0; n < 4; ++n) {
        const int R = wc + n * 16 + l15;
        bf[n] = *(const s16x8*)(&sB[R][(kk + g * 8) ^ ((R & 7) << 3)]);
      }
#pragma unroll
      for (int m = 0; m < MR; ++m)
#pragma unroll
        for (int n = 0; n < 4; ++n)
          acc[m][n] = __builtin_amdgcn_mfma_f32_16x16x32_bf16(af[m], bf[n], acc[m][n], 0, 0, 0);
    }
  }

#pragma unroll
  for (int m = 0; m < MR; ++m) {
#pragma unroll
    for (int n = 0; n < 4; ++n) {
      const int col = n0 + wc + n * 16 + l15;
      float bv = 0.f;
      if (EPI >= 1) bv = bias[col];
#pragma unroll
      for (int i = 0; i < 4; ++i) {
        const int row = m0 + wr + m * 16 + g * 4 + i;
        float v = acc[m][n][i];
        if (EPI >= 1) v += bv;
        if (EPI == 1) v = fmaxf(v, 0.f);
        if (EPI == 2) {
          v += resid[(size_t)row * N + col];
          ((float*)out)[(size_t)row * N + col] = v;
        } else {
          ((u16*)out)[(size_t)row * N + col] = f2bf(v);
        }
      }
    }
  }
}

// ---------------------------------------------------------------------------
// 256x256 8-phase GEMM (T3+T4+T5). 512 threads = 8 waves (2M x 4N), BK=64,
// 2 LDS double-buffers (128 KiB). Per iteration: consume even tile (buf0,
// phases 0-3) + odd tile (buf1, phases 4-7); issue next odd tile in ph0-3,
// next even in ph4-7; vmcnt(0) drains only at ph3/ph7 (~4 phases after
// issue). Quadrant = 2 m-tiles x 4 n-tiles x K=64 -> 16 MFMA per phase.
// B-fragments read once per K-tile (ph0/ph4), reused in regs.
// ---------------------------------------------------------------------------
template <int EPI>
__global__ __launch_bounds__(512, 2) void gemm256_kernel(
    const u16* __restrict__ A, const u16* __restrict__ BT,
    const float* __restrict__ bias, const float* __restrict__ resid,
    void* __restrict__ out, int M, int N, int K) {
  __shared__ u16 lds[2][2][256][64];  // [kbuf][0=A,1=B][row][col] = 128 KiB
  const int tid = threadIdx.x;
  const int wid = tid >> 6, lane = tid & 63;
  const int m0 = blockIdx.y * 256, n0 = blockIdx.x * 256;
  const int wr = (wid >> 2) * 128;   // 2 M-wave-groups
  const int wc = (wid & 3) * 64;     // 4 N-wave-groups
  const int l15 = lane & 15, g = lane >> 4;
  const int lr = lane >> 3;
  const int cswz = ((lane & 7) * 8) ^ (lr << 3);  // pre-swizzled source col
  const int swz = (l15 & 7) << 3;                 // read-side XOR
  const u16* Abase = A + (size_t)m0 * K;
  const u16* Bbase = BT + (size_t)n0 * K;
  const int nkt = K >> 6;

  f32x4 acc[8][4] = {};
  s16x8 bf[4][2];

  // stage one 128-row half-tile of matrix xi for K-tile t into lds[t&1][xi]
  auto issue_half = [&](const u16* Xbase, int xi, int t, int hf) {
    const int b = t & 1;
    const int r0 = hf * 128 + wid * 8;  // wave-uniform LDS base rows
    gload16(Xbase + (size_t)(r0 + lr) * K + t * 64 + cswz, &lds[b][xi][r0][0]);
    gload16(Xbase + (size_t)(r0 + 64 + lr) * K + t * 64 + cswz, &lds[b][xi][r0 + 64][0]);
  };

  // prologue: tile 0 fully staged, drained
  issue_half(Abase, 0, 0, 0);
  issue_half(Abase, 0, 0, 1);
  issue_half(Bbase, 1, 0, 0);
  issue_half(Bbase, 1, 0, 1);
  asm volatile("s_waitcnt vmcnt(0)" ::: "memory");
  __builtin_amdgcn_s_barrier();

  for (int i = 0; i < nkt; i += 2) {
    // ---- phases 0..3: consume tile i (buf0); issue tile i+1 (buf1)
#pragma unroll
    for (int p = 0; p < 4; ++p) {
      s16x8 af[2][2];
#pragma unroll
      for (int q = 0; q < 2; ++q) {
        const int R = wr + (2 * p + q) * 16 + l15;
#pragma unroll
        for (int h = 0; h < 2; ++h)
          af[q][h] = *(const s16x8*)(&lds[0][0][R][(h * 32 + g * 8) ^ swz]);
      }
      if (p == 0) {
#pragma unroll
        for (int n = 0; n < 4; ++n) {
          const int R = wc + n * 16 + l15;
#pragma unroll
          for (int h = 0; h < 2; ++h)
            bf[n][h] = *(const s16x8*)(&lds[0][1][R][(h * 32 + g * 8) ^ swz]);
        }
      }
      if (i + 1 < nkt) {  // buf1 free: last read was prev iteration ph7
        if (p == 0) issue_half(Abase, 0, i + 1, 0);
        else if (p == 1) issue_half(Abase, 0, i + 1, 1);
        else if (p == 2) issue_half(Bbase, 1, i + 1, 0);
        else issue_half(Bbase, 1, i + 1, 1);
      }
      __builtin_amdgcn_s_barrier();
      asm volatile("s_waitcnt lgkmcnt(0)" ::: "memory");
      __builtin_amdgcn_sched_barrier(0);  // rule #18: pin MFMA after the wait
      __builtin_amdgcn_s_setprio(1);
#pragma unroll
      for (int q = 0; q < 2; ++q)
#pragma unroll
        for (int n = 0; n < 4; ++n) {
          acc[2 * p + q][n] = __builtin_amdgcn_mfma_f32_16x16x32_bf16(af[q][0], bf[n][0], acc[2 * p + q][n], 0, 0, 0);
          acc[2 * p + q][n] = __builtin_amdgcn_mfma_f32_16x16x32_bf16(af[q][1], bf[n][1], acc[2 * p + q][n], 0, 0, 0);
        }
      __builtin_amdgcn_s_setprio(0);
      if (p == 3)  // tile i+1's 8 loads issued >=1 phase ago: near-free drain
        asm volatile("s_waitcnt vmcnt(0)" ::: "memory");
      __builtin_amdgcn_s_barrier();
    }
    // ---- phases 4..7: consume tile i+1 (buf1); issue tile i+2 (buf0)
    if (i + 1 < nkt) {
#pragma unroll
      for (int p = 0; p < 4; ++p) {
        s16x8 af[2][2];
#pragma unroll
        for (int q = 0; q < 2; ++q) {
          const int R = wr + (2 * p + q) * 16 + l15;
#pragma unroll
          for (int h = 0; h < 2; ++h)
            af[q][h] = *(const s16x8*)(&lds[1][0][R][(h * 32 + g * 8) ^ swz]);
        }
        if (p == 0) {
#pragma unroll
          for (int n = 0; n < 4; ++n) {
            const int R = wc + n * 16 + l15;
#pragma unroll
            for (int h = 0; h < 2; ++h)
              bf[n][h] = *(const s16x8*)(&lds[1][1][R][(h * 32 + g * 8) ^ swz]);
          }
        }
        if (i + 2 < nkt) {  // buf0 free: last read was ph3 (barrier passed)
          if (p == 0) issue_half(Abase, 0, i + 2, 0);
          else if (p == 1) issue_half(Abase, 0, i + 2, 1);
          else if (p == 2) issue_half(Bbase, 1, i + 2, 0);
          else issue_half(Bbase, 1, i + 2, 1);
        }
        __builtin_amdgcn_s_barrier();
        asm volatile("s_waitcnt lgkmcnt(0)" ::: "memory");
        __builtin_amdgcn_sched_barrier(0);
        __builtin_amdgcn_s_setprio(1);
#pragma unroll
        for (int q = 0; q < 2; ++q)
#pragma unroll
          for (int n = 0; n < 4; ++n) {
            acc[2 * p + q][n] = __builtin_amdgcn_mfma_f32_16x16x32_bf16(af[q][0], bf[n][0], acc[2 * p + q][n], 0, 0, 0);
            acc[2 * p + q][n] = __builtin_amdgcn_mfma_f32_16x16x32_bf16(af[q][1], bf[n][1], acc[2 * p + q][n], 0, 0, 0);
          }
        __builtin_amdgcn_s_setprio(0);
        if (p == 3)
          asm volatile("s_waitcnt vmcnt(0)" ::: "memory");
        __builtin_amdgcn_s_barrier();
      }
    }
  }

  // epilogue
#pragma unroll
  for (int mi = 0; mi < 8; ++mi)
#pragma unroll
    for (int n = 0; n < 4; ++n) {
      const int col = n0 + wc + n * 16 + l15;
      float bv = (EPI >= 1) ? bias[col] : 0.f;
#pragma unroll
      for (int ii = 0; ii < 4; ++ii) {
        const int row = m0 + wr + mi * 16 + g * 4 + ii;
        float v = acc[mi][n][ii];
        if (EPI >= 1) v += bv;
        if (EPI == 1) v = fmaxf(v, 0.f);
        ((u16*)out)[(size_t)row * N + col] = f2bf(v);
      }
    }
}

// ---------------------------------------------------------------------------
// MFMA causal flash attention (round-8 version, measured 81.6 us).
// Paired q-tiles {31-bx, bx}; T14 reg-prefetch staging. grid (16, B*H), 256.
// ---------------------------------------------------------------------------
__global__ __launch_bounds__(256) void attn_mfma_kernel(
    const u16* __restrict__ qkv, u16* __restrict__ o) {
  __shared__ u16 sK[64][72];    // [s][d]
  __shared__ u16 sVt[64][68];   // [d][s]
  __shared__ u16 sP[4][16][72]; // per-wave P strip [q][s]
  const int tid = threadIdx.x;
  const int b = blockIdx.y >> 4, h = blockIdx.y & 15;
  const int w = tid >> 6, lane = tid & 63;
  const int l15 = lane & 15, g = lane >> 4;
  const float c = 0.125f * 1.4426950408889634f;  // scale * log2(e)
  const int ks_r = tid >> 2, ks_c = (tid & 3) * 16;
  const int vs_s = tid & 63, vs_d = (tid >> 6) * 8;
  const u16* kbase = qkv + (size_t)(b * 2048) * 3072 + 1024 + h * 64;
  const u16* vbase = kbase + 1024;

#pragma unroll 1
  for (int pass = 0; pass < 2; ++pass) {
    const int qb = pass == 0 ? (31 - (int)blockIdx.x) : (int)blockIdx.x;

    const size_t qrow = (size_t)(b * 2048 + qb * 64 + w * 16 + l15);
    s16x8 qf0 = *(const s16x8*)(qkv + qrow * 3072 + h * 64 + g * 8);
    s16x8 qf1 = *(const s16x8*)(qkv + qrow * 3072 + h * 64 + 32 + g * 8);

    f32x4 oacc[4] = {};
    float mrow[4] = {-1e30f, -1e30f, -1e30f, -1e30f};
    float lrow[4] = {0.f, 0.f, 0.f, 0.f};  // per-lane partial; reduced in epilogue

    const int nt = qb + 1;
    uint4 kr0, kr1, vr0, vr1;
    {
      const u16* kp = kbase + (size_t)(ks_r)*3072 + ks_c;
      kr0 = *(const uint4*)kp; kr1 = *(const uint4*)(kp + 8);
      const u16* vp = vbase + (size_t)(vs_s)*3072 + vs_d;
      vr0 = *(const uint4*)vp; vr1 = *(const uint4*)(vp + 32);
    }
    for (int t = 0; t < nt; ++t) {
      __syncthreads();
      *(uint4*)(&sK[ks_r][ks_c]) = kr0;
      *(uint4*)(&sK[ks_r][ks_c + 8]) = kr1;
      {
        union { uint4 q4; u16 e[8]; } va, vb;
        va.q4 = vr0; vb.q4 = vr1;
#pragma unroll
        for (int j = 0; j < 8; ++j) sVt[vs_d + j][vs_s] = va.e[j];
#pragma unroll
        for (int j = 0; j < 8; ++j) sVt[vs_d + 32 + j][vs_s] = vb.e[j];
      }
      __syncthreads();
      if (t + 1 < nt) {
        const u16* kp = kbase + (size_t)((t + 1) * 64 + ks_r) * 3072 + ks_c;
        kr0 = *(const uint4*)kp; kr1 = *(const uint4*)(kp + 8);
        const u16* vp = vbase + (size_t)((t + 1) * 64 + vs_s) * 3072 + vs_d;
        vr0 = *(const uint4*)vp; vr1 = *(const uint4*)(vp + 32);
      }

      f32x4 st[4];
#pragma unroll
      for (int n = 0; n < 4; ++n) {
        s16x8 k0 = *(const s16x8*)(&sK[n * 16 + l15][g * 8]);
        s16x8 k1 = *(const s16x8*)(&sK[n * 16 + l15][32 + g * 8]);
        f32x4 a = {};
        a = __builtin_amdgcn_mfma_f32_16x16x32_bf16(qf0, k0, a, 0, 0, 0);
        a = __builtin_amdgcn_mfma_f32_16x16x32_bf16(qf1, k1, a, 0, 0, 0);
        st[n] = a;
      }
      if (t == qb) {
#pragma unroll
        for (int n = 0; n < 4; ++n)
#pragma unroll
          for (int i = 0; i < 4; ++i) {
            const int srel = n * 16 + l15, qrel = w * 16 + 4 * g + i;
            if (srel > qrel) st[n][i] = -1e30f;
          }
      }
      float pm[4];
#pragma unroll
      for (int i = 0; i < 4; ++i)
        pm[i] = fmaxf(fmaxf(st[0][i], st[1][i]), fmaxf(st[2][i], st[3][i]));
#pragma unroll
      for (int msk = 1; msk < 16; msk <<= 1)
#pragma unroll
        for (int i = 0; i < 4; ++i) pm[i] = fmaxf(pm[i], __shfl_xor(pm[i], msk));
      float corr[4];
#pragma unroll
      for (int i = 0; i < 4; ++i) {
        const float mnew = fmaxf(mrow[i], pm[i]);
        corr[i] = exp2f((mrow[i] - mnew) * c);
        mrow[i] = mnew;
        lrow[i] *= corr[i];
      }
#pragma unroll
      for (int dt = 0; dt < 4; ++dt)
#pragma unroll
        for (int i = 0; i < 4; ++i) oacc[dt][i] *= corr[i];
      float p[4][4];
#pragma unroll
      for (int n = 0; n < 4; ++n)
#pragma unroll
        for (int i = 0; i < 4; ++i) p[n][i] = exp2f((st[n][i] - mrow[i]) * c);
#pragma unroll
      for (int i = 0; i < 4; ++i)
        lrow[i] += (p[0][i] + p[1][i]) + (p[2][i] + p[3][i]);
#pragma unroll
      for (int n = 0; n < 4; ++n)
#pragma unroll
        for (int i = 0; i < 4; ++i)
          sP[w][4 * g + i][n * 16 + l15] = f2bf(p[n][i]);
      s16x8 pf0 = *(const s16x8*)(&sP[w][l15][g * 8]);
      s16x8 pf1 = *(const s16x8*)(&sP[w][l15][32 + g * 8]);
#pragma unroll
      for (int dt = 0; dt < 4; ++dt) {
        s16x8 vf0 = ld_s16x8_a8(&sVt[dt * 16 + l15][g * 8]);
        s16x8 vf1 = ld_s16x8_a8(&sVt[dt * 16 + l15][32 + g * 8]);
        oacc[dt] = __builtin_amdgcn_mfma_f32_16x16x32_bf16(pf0, vf0, oacc[dt], 0, 0, 0);
        oacc[dt] = __builtin_amdgcn_mfma_f32_16x16x32_bf16(pf1, vf1, oacc[dt], 0, 0, 0);
      }
    }

#pragma unroll
    for (int msk = 1; msk < 16; msk <<= 1)
#pragma unroll
      for (int i = 0; i < 4; ++i) lrow[i] += __shfl_xor(lrow[i], msk);
    float inv[4];
#pragma unroll
    for (int i = 0; i < 4; ++i) inv[i] = 1.f / lrow[i];
#pragma unroll
    for (int dt = 0; dt < 4; ++dt)
#pragma unroll
      for (int i = 0; i < 4; ++i) {
        const size_t row = (size_t)(b * 2048 + qb * 64 + w * 16 + 4 * g + i);
        o[row * 1024 + h * 64 + dt * 16 + l15] = f2bf(oacc[dt][i] * inv[i]);
      }
  }
}

// ---------------------------------------------------------------------------
extern "C" void kernel_launch(void* const* d_in, const int* in_sizes, int n_in,
                              void* d_out, int out_size, void* d_ws, size_t ws_size,
                              hipStream_t stream) {
  const float* x     = (const float*)d_in[0];
  const float* Wq    = (const float*)d_in[1];
  const float* Wk    = (const float*)d_in[2];
  const float* Wv    = (const float*)d_in[3];
  const float* Wproj = (const float*)d_in[4];
  const float* bproj = (const float*)d_in[5];
  const float* W1    = (const float*)d_in[6];
  const float* b1    = (const float*)d_in[7];
  const float* W2    = (const float*)d_in[8];
  const float* b2    = (const float*)d_in[9];
  const float* g1    = (const float*)d_in[10];
  const float* be1   = (const float*)d_in[11];
  const float* g2    = (const float*)d_in[12];
  const float* be2   = (const float*)d_in[13];
  float* out = (float*)d_out;

  u16* WqkvT  = (u16*)d_ws;                    // [3072][1024] bf16
  u16* WprojT = WqkvT + (size_t)3072 * 1024;   // [1024][1024]
  u16* W1T    = WprojT + (size_t)1024 * 1024;  // [4096][1024]
  u16* W2T    = W1T + (size_t)4096 * 1024;     // [1024][4096]
  u16* hbuf   = W2T + (size_t)1024 * 4096;     // [4096][1024]
  u16* qkv    = hbuf + (size_t)4096 * 1024;    // [4096][3072]
  u16* obuf   = qkv + (size_t)4096 * 3072;     // [4096][1024]
  float* x2   = (float*)(obuf + (size_t)4096 * 1024);  // [4096][1024] fp32
  u16* a1     = (u16*)(x2 + (size_t)4096 * 1024);      // [4096][4096]

  transpose_f32_bf16<<<dim3(1, 16, 16), 256, 0, stream>>>(Wq, WqkvT,                      64, 65536, 65536, 1024);
  transpose_f32_bf16<<<dim3(1, 16, 16), 256, 0, stream>>>(Wk, WqkvT + (size_t)1024 * 1024, 64, 65536, 65536, 1024);
  transpose_f32_bf16<<<dim3(1, 16, 16), 256, 0, stream>>>(Wv, WqkvT + (size_t)2048 * 1024, 64, 65536, 65536, 1024);
  transpose_f32_bf16<<<dim3(16, 16, 1), 256, 0, stream>>>(Wproj, WprojT, 1024, 0, 0, 1024);
  transpose_f32_bf16<<<dim3(64, 16, 1), 256, 0, stream>>>(W1, W1T, 4096, 0, 0, 1024);
  transpose_f32_bf16<<<dim3(16, 64, 1), 256, 0, stream>>>(W2, W2T, 1024, 0, 0, 4096);

  ln_kernel<<<4096, 256, 0, stream>>>(x, g1, be1, hbuf);
  gemm_kernel<0, 128><<<dim3(24, 32), 256, 0, stream>>>(hbuf, WqkvT, nullptr, nullptr, qkv, 4096, 3072, 1024);
  attn_mfma_kernel<<<dim3(16, 32), 256, 0, stream>>>(qkv, obuf);
  gemm_kernel<2, 64><<<dim3(8, 64), 256, 0, stream>>>(obuf, WprojT, bproj, x, x2, 4096, 1024, 1024);
  ln_kernel<<<4096, 256, 0, stream>>>(x2, g2, be2, hbuf);
  // FF1: 256x256 8-phase kernel (grid 16x16 = 256 blocks = 1/CU)
  gemm256_kernel<1><<<dim3(16, 16), 512, 0, stream>>>(hbuf, W1T, b1, nullptr, a1, 4096, 4096, 1024);
  gemm_kernel<2, 64><<<dim3(8, 64), 256, 0, stream>>>(a1, W2T, b2, x2, out, 4096, 1024, 4096);
}